// Round 6
// baseline (736.814 us; speedup 1.0000x reference)
//
#include <hip/hip_runtime.h>
#include <math.h>
#include <stdint.h>

namespace {
constexpr float kDT  = 0.01f;   // DT / SUBSTEP, SUBSTEP == 1
constexpr int   kIter = 10;
constexpr float kH   = -2.0f;
constexpr float kEps = 1e-5f;
constexpr int   kB = 8;
constexpr int   kN = 50000;
constexpr int   kE = 200000;
constexpr int   kBN = kB * kN;
constexpr int   kNB = (kN + 255) / 256;   // blocks for per-vertex scan
constexpr int   kBins = 1024;             // degree histogram bins (clamped)
}

// ---------------- CSR build (once per launch) ----------------

__global__ void count_kernel(const int2* __restrict__ Cdist, int* __restrict__ deg) {
    int e = blockIdx.x * blockDim.x + threadIdx.x;
    if (e >= kE) return;
    int2 c = Cdist[e];
    atomicAdd(&deg[c.x], 1);
    atomicAdd(&deg[c.y], 1);
}

__global__ void partial_sum_kernel(const int* __restrict__ deg, int* __restrict__ blkSum) {
    __shared__ int s[256];
    int i = blockIdx.x * 256 + threadIdx.x;
    s[threadIdx.x] = (i < kN) ? deg[i] : 0;
    __syncthreads();
    for (int off = 128; off > 0; off >>= 1) {
        if (threadIdx.x < off) s[threadIdx.x] += s[threadIdx.x + off];
        __syncthreads();
    }
    if (threadIdx.x == 0) blkSum[blockIdx.x] = s[0];
}

__global__ void scan_sums_kernel(const int* __restrict__ blkSum, int* __restrict__ blkOff) {
    __shared__ int s[kNB];
    int tid = threadIdx.x;                 // 256 threads >= kNB
    if (tid < kNB) s[tid] = blkSum[tid];
    __syncthreads();
    if (tid == 0) {
        int acc = 0;
        for (int i = 0; i < kNB; ++i) { int v = s[i]; s[i] = acc; acc += v; }
    }
    __syncthreads();
    if (tid < kNB) blkOff[tid] = s[tid];
}

__global__ void scatter_scan_kernel(const int* __restrict__ deg,
                                    const int* __restrict__ blkOff,
                                    int* __restrict__ start) {
    __shared__ int s[256];
    int tid = threadIdx.x;
    int i = blockIdx.x * 256 + tid;
    int c = (i < kN) ? deg[i] : 0;
    s[tid] = c;
    __syncthreads();
    for (int off = 1; off < 256; off <<= 1) {      // inclusive Hillis-Steele
        int v = (tid >= off) ? s[tid - off] : 0;
        __syncthreads();
        s[tid] += v;
        __syncthreads();
    }
    int incl = s[tid];
    int excl = incl - c;
    if (i < kN) start[i] = blkOff[blockIdx.x] + excl;
    if (i == kN - 1) start[kN] = blkOff[blockIdx.x] + incl;   // == 2E
}

// inc id = 2*e + side. Fill order nondeterministic (atomics); summation-order
// FP wiggle is far below the tolerance (validated R1-R5).
__global__ void fill_kernel(const int2* __restrict__ Cdist, int* __restrict__ cursor,
                            int* __restrict__ inc) {
    int e = blockIdx.x * blockDim.x + threadIdx.x;
    if (e >= kE) return;
    int2 c = Cdist[e];
    int p0 = atomicAdd(&cursor[c.x], 1);
    inc[p0] = 2 * e;
    int p1 = atomicAdd(&cursor[c.y], 1);
    inc[p1] = 2 * e + 1;
}

// ---------------- degree-sorted dispatch order ----------------

__global__ void hist_kernel(const int* __restrict__ deg, int* __restrict__ hist) {
    int v = blockIdx.x * blockDim.x + threadIdx.x;
    if (v >= kN) return;
    int d = deg[v];
    if (d > kBins - 1) d = kBins - 1;
    atomicAdd(&hist[d], 1);
}

// cursB[d] = sum_{d' > d} hist[d']   (descending-degree base offsets)
__global__ void hist_scan_kernel(const int* __restrict__ hist, int* __restrict__ cursB) {
    __shared__ int s[kBins];
    int tid = threadIdx.x;                 // 1024 threads
    s[tid] = hist[tid];
    __syncthreads();
    if (tid == 0) {
        int acc = 0;
        for (int d = kBins - 1; d >= 0; --d) { int h = s[d]; s[d] = acc; acc += h; }
    }
    __syncthreads();
    cursB[tid] = s[tid];
}

// Placement within a bin is atomic-order nondeterministic, but order[] only
// selects WHICH thread handles a vertex — no FP summation order depends on it.
__global__ void order_scatter_kernel(const int* __restrict__ deg, int* __restrict__ cursB,
                                     int* __restrict__ order) {
    int v = blockIdx.x * blockDim.x + threadIdx.x;
    if (v >= kN) return;
    int d = deg[v];
    if (d > kBins - 1) d = kBins - 1;
    int pos = atomicAdd(&cursB[d], 1);
    order[pos] = v;
}

// ---------------- predict + batch-minor re-layout ----------------

// P[v][b] = {x,y,z predicted, w};  WC[v][b] = {w, comp}
__global__ void predict_kernel(const float* __restrict__ V,
                               const float* __restrict__ Vvel,
                               const float* __restrict__ Vw,
                               const float* __restrict__ Vcomp,
                               const float* __restrict__ Vmass,
                               const float* __restrict__ Vforce,
                               float4* __restrict__ P,
                               float2* __restrict__ WC) {
    int v = blockIdx.x * blockDim.x + threadIdx.x;
    if (v >= kN) return;
#pragma unroll
    for (int b = 0; b < kB; ++b) {
        int idx = b * kN + v;
        int k = idx * 3;
        float m = Vmass[idx];
        float4 r;
        float vpx = Vvel[k + 0] + (kDT * Vforce[k + 0]) / m;   // (dt*F)/m, reference order
        float vpy = Vvel[k + 1] + (kDT * Vforce[k + 1]) / m;
        float vpz = Vvel[k + 2] + (kDT * Vforce[k + 2]) / m;
        float w = Vw[idx];
        r.x = V[k + 0] + kDT * vpx;
        r.y = V[k + 1] + kDT * vpy;
        r.z = V[k + 2] + kDT * vpz;
        r.w = w;
        P[v * 8 + b] = r;
        WC[v * 8 + b] = make_float2(w, Vcomp[idx]);
    }
}

// Per-slot static data: SS[k] = {other, init_d bits}; ASrec[k][b] = {A, 1/(S+A)}
__global__ void slots_build_kernel(const int* __restrict__ inc,
                                   const int2* __restrict__ Cdist,
                                   const float* __restrict__ Cinit,
                                   const float2* __restrict__ WC,
                                   int2* __restrict__ SS,
                                   float2* __restrict__ ASrec) {
    int k = blockIdx.x * blockDim.x + threadIdx.x;
    if (k >= 2 * kE) return;
    int ic = inc[k];
    int e = ic >> 1;
    int2 c = Cdist[e];
    int other = (ic & 1) ? c.x : c.y;
    SS[k] = make_int2(other, __float_as_int(Cinit[e]));
#pragma unroll
    for (int b = 0; b < kB; ++b) {
        float2 wi = WC[c.x * 8 + b];
        float2 wj = WC[c.y * 8 + b];
        float A = (wi.y + wj.y) * 0.5f;
        float S = wi.x + wj.x;
        if (S == 0.0f) S = INFINITY;
        ASrec[k * 8 + b] = make_float2(A, 1.0f / (S + A));
    }
}

// ---------------- fused Jacobi sweep ----------------
// Thread = (vertex, batch); b = lane&7 so all accesses are line-coalesced:
// P own/neighbor = full 64B lines shared by 8 lanes, SS broadcast, L 32B runs.
// Vertices visited via degree-sorted order[] -> uniform k-loop trip count per
// wave (kills divergence waste). Ld is bitwise identical from both endpoints,
// so per-slot L (owned by exactly one thread) evolves consistently in place.
template <bool LAST>
__global__ void sweep_kernel(const float4* __restrict__ Psrc,
                             float4* __restrict__ Pdst,
                             float* __restrict__ L,
                             const int2* __restrict__ SS,
                             const float2* __restrict__ ASrec,
                             const int* __restrict__ start,
                             const int* __restrict__ order,
                             const float* __restrict__ V,
                             float* __restrict__ outV,
                             float* __restrict__ outVel) {
    int t = blockIdx.x * blockDim.x + threadIdx.x;
    if (t >= 8 * kN) return;
    int g = t >> 3;
    int b = t & 7;
    int v = order[g];
    float4 own = Psrc[(size_t)v * 8 + b];
    int s0 = start[v], s1 = start[v + 1];
    float ax = 0.f, ay = 0.f, az = 0.f;
    for (int k = s0; k < s1; ++k) {
        int2 ss = SS[k];
        float4 oth = Psrc[(size_t)ss.x * 8 + b];
        float2 a = ASrec[(size_t)k * 8 + b];
        float Lold = L[(size_t)k * 8 + b];
        float dx = own.x - oth.x;
        float dy = own.y - oth.y;
        float dz = own.z - oth.z;
        float D = sqrtf(dx * dx + dy * dy + dz * dz);
        float C = D - __int_as_float(ss.y);
        float Ld = (-C - a.x * Lold) * a.y;
        L[(size_t)k * 8 + b] = Lold + Ld;
        float rD = 1.0f / D;
        ax += Ld * (dx * rD);
        ay += Ld * (dy * rD);
        az += Ld * (dz * rD);
    }
    float px = own.x + own.w * ax;
    float py = own.y + own.w * ay;
    float pz = own.z + own.w * az;
    if (!LAST) {
        Pdst[(size_t)v * 8 + b] = make_float4(px, py, pz, own.w);
    } else {
        int k3 = (b * kN + v) * 3;
        float vx = V[k3], vy = V[k3 + 1], vz0 = V[k3 + 2];

        bool col = (pz < kH) && (vz0 > kH);
        float h_prev = vz0 - kH;
        float h_after = kH - pz;
        float denom = col ? (h_prev + h_after) : 1.0f;
        float tt = h_prev / denom;

        float x  = col ? (vx + tt * (px - vx)) : px;
        float y  = col ? (vy + tt * (py - vy)) : py;
        float z1 = col ? (kH + kEps) : pz;

        bool vio = (z1 < kH) && (vz0 < kH);
        float z2 = vio ? (kH + kEps) : z1;

        float velx = (x  - vx ) / kDT;
        float vely = (y  - vy ) / kDT;
        float velz = (z2 - vz0) / kDT;
        velz = col ? -velz : velz;
        velz = vio ? 0.0f : velz;

        outV[k3] = x;  outV[k3 + 1] = y;  outV[k3 + 2] = z2;
        outVel[k3] = velx; outVel[k3 + 1] = vely; outVel[k3 + 2] = velz;
    }
}

// ---------------- launch ----------------

extern "C" void kernel_launch(void* const* d_in, const int* in_sizes, int n_in,
                              void* d_out, int out_size, void* d_ws, size_t ws_size,
                              hipStream_t stream) {
    const float* V      = (const float*)d_in[0];
    const float* Vvel   = (const float*)d_in[1];
    const float* Vw     = (const float*)d_in[2];
    const float* Vcomp  = (const float*)d_in[3];
    const float* Vmass  = (const float*)d_in[4];
    const float* Vforce = (const float*)d_in[5];
    const float* Cinit  = (const float*)d_in[6];
    const int2*  Cdist  = (const int2*)d_in[7];

    char* p = (char*)d_ws;
    auto alloc = [&](size_t bytes) -> void* {
        p = (char*)(((uintptr_t)p + 255) & ~(uintptr_t)255);
        void* r = (void*)p;
        p += bytes;
        return r;
    };

    float4* PA     = (float4*)alloc((size_t)kN * 8 * sizeof(float4));       // 6.4 MB
    float4* PB     = (float4*)alloc((size_t)kN * 8 * sizeof(float4));       // 6.4 MB
    float*  L      = (float*)alloc((size_t)2 * kE * 8 * sizeof(float));     // 12.8 MB
    float2* ASrec  = (float2*)alloc((size_t)2 * kE * 8 * sizeof(float2));   // 25.6 MB
    int2*   SS     = (int2*)alloc((size_t)2 * kE * sizeof(int2));           // 3.2 MB
    float2* WC     = (float2*)alloc((size_t)kN * 8 * sizeof(float2));       // 3.2 MB
    int*    start  = (int*)alloc((size_t)(kN + 1) * sizeof(int));
    int*    deg    = (int*)alloc((size_t)kN * sizeof(int));
    int*    cursor = (int*)alloc((size_t)kN * sizeof(int));
    int*    inc    = (int*)alloc((size_t)2 * kE * sizeof(int));
    int*    blkSum = (int*)alloc((size_t)kNB * sizeof(int));
    int*    blkOff = (int*)alloc((size_t)kNB * sizeof(int));
    int*    hist   = (int*)alloc((size_t)kBins * sizeof(int));
    int*    cursB  = (int*)alloc((size_t)kBins * sizeof(int));
    int*    order  = (int*)alloc((size_t)kN * sizeof(int));

    const int TB = 256;
    dim3 blk(TB);
    dim3 gE((kE + TB - 1) / TB);
    dim3 g2E((2 * kE + TB - 1) / TB);
    dim3 gN((kN + TB - 1) / TB);
    dim3 g8N((8 * kN + TB - 1) / TB);

    // CSR build
    hipMemsetAsync(deg, 0, kN * sizeof(int), stream);
    count_kernel<<<gE, blk, 0, stream>>>(Cdist, deg);
    partial_sum_kernel<<<dim3(kNB), blk, 0, stream>>>(deg, blkSum);
    scan_sums_kernel<<<dim3(1), blk, 0, stream>>>(blkSum, blkOff);
    scatter_scan_kernel<<<dim3(kNB), blk, 0, stream>>>(deg, blkOff, start);
    hipMemcpyAsync(cursor, start, kN * sizeof(int), hipMemcpyDeviceToDevice, stream);
    fill_kernel<<<gE, blk, 0, stream>>>(Cdist, cursor, inc);

    // degree-sorted dispatch order (descending: longest blocks first)
    hipMemsetAsync(hist, 0, kBins * sizeof(int), stream);
    hist_kernel<<<gN, blk, 0, stream>>>(deg, hist);
    hist_scan_kernel<<<dim3(1), dim3(kBins), 0, stream>>>(hist, cursB);
    order_scatter_kernel<<<gN, blk, 0, stream>>>(deg, cursB, order);

    // predict + batch-minor layout, then per-slot invariants
    predict_kernel<<<gN, blk, 0, stream>>>(V, Vvel, Vw, Vcomp, Vmass, Vforce, PA, WC);
    slots_build_kernel<<<g2E, blk, 0, stream>>>(inc, Cdist, Cinit, WC, SS, ASrec);
    hipMemsetAsync(L, 0, (size_t)2 * kE * 8 * sizeof(float), stream);

    float* outV   = (float*)d_out;
    float* outVel = outV + (size_t)kBN * 3;

    for (int it = 0; it < kIter; ++it) {
        float4* src = (it & 1) ? PB : PA;
        float4* dst = (it & 1) ? PA : PB;
        if (it < kIter - 1) {
            sweep_kernel<false><<<g8N, blk, 0, stream>>>(src, dst, L, SS, ASrec, start,
                                                         order, V, outV, outVel);
        } else {
            sweep_kernel<true><<<g8N, blk, 0, stream>>>(src, dst, L, SS, ASrec, start,
                                                        order, V, outV, outVel);
        }
    }
}

// Round 7
// 393.085 us; speedup vs baseline: 1.8744x; 1.8744x over previous
//
#include <hip/hip_runtime.h>
#include <math.h>
#include <stdint.h>

namespace {
constexpr float kDT  = 0.01f;   // DT / SUBSTEP, SUBSTEP == 1
constexpr int   kIter = 10;
constexpr float kH   = -2.0f;
constexpr float kEps = 1e-5f;
constexpr int   kB = 8;
constexpr int   kN = 50000;
constexpr int   kE = 200000;
constexpr int   kBN = kB * kN;
constexpr int   kNB = (kN + 255) / 256;   // 196 blocks for per-vertex kernels
constexpr int   kBins = 64;               // degree bins (clamped)
constexpr int   kM = kBins * kNB;         // (bin, block) table size
}

// ---------------- CSR build (once per launch) ----------------

__global__ void count_kernel(const int2* __restrict__ Cdist, int* __restrict__ deg) {
    int e = blockIdx.x * blockDim.x + threadIdx.x;
    if (e >= kE) return;
    int2 c = Cdist[e];
    atomicAdd(&deg[c.x], 1);
    atomicAdd(&deg[c.y], 1);
}

__global__ void partial_sum_kernel(const int* __restrict__ deg, int* __restrict__ blkSum) {
    __shared__ int s[256];
    int i = blockIdx.x * 256 + threadIdx.x;
    s[threadIdx.x] = (i < kN) ? deg[i] : 0;
    __syncthreads();
    for (int off = 128; off > 0; off >>= 1) {
        if (threadIdx.x < off) s[threadIdx.x] += s[threadIdx.x + off];
        __syncthreads();
    }
    if (threadIdx.x == 0) blkSum[blockIdx.x] = s[0];
}

__global__ void scan_sums_kernel(const int* __restrict__ blkSum, int* __restrict__ blkOff) {
    __shared__ int s[kNB];
    int tid = threadIdx.x;                 // 256 threads >= kNB
    if (tid < kNB) s[tid] = blkSum[tid];
    __syncthreads();
    if (tid == 0) {
        int acc = 0;
        for (int i = 0; i < kNB; ++i) { int v = s[i]; s[i] = acc; acc += v; }
    }
    __syncthreads();
    if (tid < kNB) blkOff[tid] = s[tid];
}

__global__ void scatter_scan_kernel(const int* __restrict__ deg,
                                    const int* __restrict__ blkOff,
                                    int* __restrict__ start) {
    __shared__ int s[256];
    int tid = threadIdx.x;
    int i = blockIdx.x * 256 + tid;
    int c = (i < kN) ? deg[i] : 0;
    s[tid] = c;
    __syncthreads();
    for (int off = 1; off < 256; off <<= 1) {      // inclusive Hillis-Steele
        int v = (tid >= off) ? s[tid - off] : 0;
        __syncthreads();
        s[tid] += v;
        __syncthreads();
    }
    int incl = s[tid];
    int excl = incl - c;
    if (i < kN) start[i] = blkOff[blockIdx.x] + excl;
    if (i == kN - 1) start[kN] = blkOff[blockIdx.x] + incl;   // == 2E
}

// inc id = 2*e + side. Fill order nondeterministic (atomics); summation-order
// FP wiggle is far below the tolerance (validated R1-R6).
__global__ void fill_kernel(const int2* __restrict__ Cdist, int* __restrict__ cursor,
                            int* __restrict__ inc) {
    int e = blockIdx.x * blockDim.x + threadIdx.x;
    if (e >= kE) return;
    int2 c = Cdist[e];
    int p0 = atomicAdd(&cursor[c.x], 1);
    inc[p0] = 2 * e;
    int p1 = atomicAdd(&cursor[c.y], 1);
    inc[p1] = 2 * e + 1;
}

// ---------------- degree-sorted dispatch order (contention-free) ----------------

__device__ __forceinline__ int clamp_deg(int d) {
    return d > kBins - 1 ? kBins - 1 : d;
}

// Per-block LDS histogram -> blkHist[(bins-1-d)*kNB + block]  (bin-descending)
__global__ void blk_hist_kernel(const int* __restrict__ deg, int* __restrict__ blkHist) {
    __shared__ int lh[kBins];
    int tid = threadIdx.x;
    if (tid < kBins) lh[tid] = 0;
    __syncthreads();
    int v = blockIdx.x * 256 + tid;
    if (v < kN) atomicAdd(&lh[clamp_deg(deg[v])], 1);   // LDS atomic: cheap
    __syncthreads();
    if (tid < kBins) blkHist[(kBins - 1 - tid) * kNB + blockIdx.x] = lh[tid];
}

// Exclusive scan of blkHist[0..kM) -> scanned[0..kM). Single block, 1024 thr.
__global__ void sort_scan_kernel(const int* __restrict__ in, int* __restrict__ out) {
    __shared__ int part[1024];
    int tid = threadIdx.x;
    const int CH = (kM + 1023) / 1024;
    int lo = tid * CH;
    int hi = lo + CH; if (hi > kM) hi = kM;
    int s = 0;
    for (int m = lo; m < hi; ++m) s += in[m];
    part[tid] = s;
    __syncthreads();
    for (int off = 1; off < 1024; off <<= 1) {
        int v = (tid >= off) ? part[tid - off] : 0;
        __syncthreads();
        part[tid] += v;
        __syncthreads();
    }
    int base = tid ? part[tid - 1] : 0;
    for (int m = lo; m < hi; ++m) { out[m] = base; base += in[m]; }
}

// Scatter: global base from scanned[], local rank via LDS atomic. Rank order
// within a bin is nondeterministic, but order[] only chooses WHICH thread
// handles a vertex — per-vertex math and output addresses are fixed.
__global__ void order_scatter_kernel(const int* __restrict__ deg,
                                     const int* __restrict__ scanned,
                                     int* __restrict__ order) {
    __shared__ int lh[kBins];
    int tid = threadIdx.x;
    if (tid < kBins) lh[tid] = 0;
    __syncthreads();
    int v = blockIdx.x * 256 + tid;
    if (v < kN) {
        int d = clamp_deg(deg[v]);
        int lr = atomicAdd(&lh[d], 1);                  // LDS atomic: cheap
        int pos = scanned[(kBins - 1 - d) * kNB + blockIdx.x] + lr;
        order[pos] = v;
    }
}

// ---------------- predict + batch-minor re-layout ----------------

// P[v][b] = {x,y,z predicted, w};  WC[v][b] = {w, comp}
__global__ void predict_kernel(const float* __restrict__ V,
                               const float* __restrict__ Vvel,
                               const float* __restrict__ Vw,
                               const float* __restrict__ Vcomp,
                               const float* __restrict__ Vmass,
                               const float* __restrict__ Vforce,
                               float4* __restrict__ P,
                               float2* __restrict__ WC) {
    int v = blockIdx.x * blockDim.x + threadIdx.x;
    if (v >= kN) return;
#pragma unroll
    for (int b = 0; b < kB; ++b) {
        int idx = b * kN + v;
        int k = idx * 3;
        float m = Vmass[idx];
        float4 r;
        float vpx = Vvel[k + 0] + (kDT * Vforce[k + 0]) / m;   // (dt*F)/m, reference order
        float vpy = Vvel[k + 1] + (kDT * Vforce[k + 1]) / m;
        float vpz = Vvel[k + 2] + (kDT * Vforce[k + 2]) / m;
        float w = Vw[idx];
        r.x = V[k + 0] + kDT * vpx;
        r.y = V[k + 1] + kDT * vpy;
        r.z = V[k + 2] + kDT * vpz;
        r.w = w;
        P[v * 8 + b] = r;
        WC[v * 8 + b] = make_float2(w, Vcomp[idx]);
    }
}

// Per-slot static data: SS[k] = {other, init_d bits}; ASrec[k][b] = {A, 1/(S+A)}
__global__ void slots_build_kernel(const int* __restrict__ inc,
                                   const int2* __restrict__ Cdist,
                                   const float* __restrict__ Cinit,
                                   const float2* __restrict__ WC,
                                   int2* __restrict__ SS,
                                   float2* __restrict__ ASrec) {
    int k = blockIdx.x * blockDim.x + threadIdx.x;
    if (k >= 2 * kE) return;
    int ic = inc[k];
    int e = ic >> 1;
    int2 c = Cdist[e];
    int other = (ic & 1) ? c.x : c.y;
    SS[k] = make_int2(other, __float_as_int(Cinit[e]));
#pragma unroll
    for (int b = 0; b < kB; ++b) {
        float2 wi = WC[c.x * 8 + b];
        float2 wj = WC[c.y * 8 + b];
        float A = (wi.y + wj.y) * 0.5f;
        float S = wi.x + wj.x;
        if (S == 0.0f) S = INFINITY;
        ASrec[k * 8 + b] = make_float2(A, 1.0f / (S + A));
    }
}

// ---------------- fused Jacobi sweep ----------------
// Thread = (vertex, batch); b = lane&7 so all accesses are line-coalesced:
// P own/neighbor = full 64B lines shared by 8 lanes, SS broadcast, L 32B runs.
// Vertices visited via degree-sorted order[] -> uniform k-loop trip count per
// wave (kills divergence waste). Ld is bitwise identical from both endpoints,
// so per-slot L (owned by exactly one thread) evolves consistently in place.
template <bool LAST>
__global__ void sweep_kernel(const float4* __restrict__ Psrc,
                             float4* __restrict__ Pdst,
                             float* __restrict__ L,
                             const int2* __restrict__ SS,
                             const float2* __restrict__ ASrec,
                             const int* __restrict__ start,
                             const int* __restrict__ order,
                             const float* __restrict__ V,
                             float* __restrict__ outV,
                             float* __restrict__ outVel) {
    int t = blockIdx.x * blockDim.x + threadIdx.x;
    if (t >= 8 * kN) return;
    int g = t >> 3;
    int b = t & 7;
    int v = order[g];
    float4 own = Psrc[(size_t)v * 8 + b];
    int s0 = start[v], s1 = start[v + 1];
    float ax = 0.f, ay = 0.f, az = 0.f;
    for (int k = s0; k < s1; ++k) {
        int2 ss = SS[k];
        float4 oth = Psrc[(size_t)ss.x * 8 + b];
        float2 a = ASrec[(size_t)k * 8 + b];
        float Lold = L[(size_t)k * 8 + b];
        float dx = own.x - oth.x;
        float dy = own.y - oth.y;
        float dz = own.z - oth.z;
        float D = sqrtf(dx * dx + dy * dy + dz * dz);
        float C = D - __int_as_float(ss.y);
        float Ld = (-C - a.x * Lold) * a.y;
        L[(size_t)k * 8 + b] = Lold + Ld;
        float rD = 1.0f / D;
        ax += Ld * (dx * rD);
        ay += Ld * (dy * rD);
        az += Ld * (dz * rD);
    }
    float px = own.x + own.w * ax;
    float py = own.y + own.w * ay;
    float pz = own.z + own.w * az;
    if (!LAST) {
        Pdst[(size_t)v * 8 + b] = make_float4(px, py, pz, own.w);
    } else {
        int k3 = (b * kN + v) * 3;
        float vx = V[k3], vy = V[k3 + 1], vz0 = V[k3 + 2];

        bool col = (pz < kH) && (vz0 > kH);
        float h_prev = vz0 - kH;
        float h_after = kH - pz;
        float denom = col ? (h_prev + h_after) : 1.0f;
        float tt = h_prev / denom;

        float x  = col ? (vx + tt * (px - vx)) : px;
        float y  = col ? (vy + tt * (py - vy)) : py;
        float z1 = col ? (kH + kEps) : pz;

        bool vio = (z1 < kH) && (vz0 < kH);
        float z2 = vio ? (kH + kEps) : z1;

        float velx = (x  - vx ) / kDT;
        float vely = (y  - vy ) / kDT;
        float velz = (z2 - vz0) / kDT;
        velz = col ? -velz : velz;
        velz = vio ? 0.0f : velz;

        outV[k3] = x;  outV[k3 + 1] = y;  outV[k3 + 2] = z2;
        outVel[k3] = velx; outVel[k3 + 1] = vely; outVel[k3 + 2] = velz;
    }
}

// ---------------- launch ----------------

extern "C" void kernel_launch(void* const* d_in, const int* in_sizes, int n_in,
                              void* d_out, int out_size, void* d_ws, size_t ws_size,
                              hipStream_t stream) {
    const float* V      = (const float*)d_in[0];
    const float* Vvel   = (const float*)d_in[1];
    const float* Vw     = (const float*)d_in[2];
    const float* Vcomp  = (const float*)d_in[3];
    const float* Vmass  = (const float*)d_in[4];
    const float* Vforce = (const float*)d_in[5];
    const float* Cinit  = (const float*)d_in[6];
    const int2*  Cdist  = (const int2*)d_in[7];

    char* p = (char*)d_ws;
    auto alloc = [&](size_t bytes) -> void* {
        p = (char*)(((uintptr_t)p + 255) & ~(uintptr_t)255);
        void* r = (void*)p;
        p += bytes;
        return r;
    };

    float4* PA     = (float4*)alloc((size_t)kN * 8 * sizeof(float4));       // 6.4 MB
    float4* PB     = (float4*)alloc((size_t)kN * 8 * sizeof(float4));       // 6.4 MB
    float*  L      = (float*)alloc((size_t)2 * kE * 8 * sizeof(float));     // 12.8 MB
    float2* ASrec  = (float2*)alloc((size_t)2 * kE * 8 * sizeof(float2));   // 25.6 MB
    int2*   SS     = (int2*)alloc((size_t)2 * kE * sizeof(int2));           // 3.2 MB
    float2* WC     = (float2*)alloc((size_t)kN * 8 * sizeof(float2));       // 3.2 MB
    int*    start  = (int*)alloc((size_t)(kN + 1) * sizeof(int));
    int*    deg    = (int*)alloc((size_t)kN * sizeof(int));
    int*    cursor = (int*)alloc((size_t)kN * sizeof(int));
    int*    inc    = (int*)alloc((size_t)2 * kE * sizeof(int));
    int*    blkSum = (int*)alloc((size_t)kNB * sizeof(int));
    int*    blkOff = (int*)alloc((size_t)kNB * sizeof(int));
    int*    blkHist= (int*)alloc((size_t)kM * sizeof(int));
    int*    scanned= (int*)alloc((size_t)kM * sizeof(int));
    int*    order  = (int*)alloc((size_t)kN * sizeof(int));

    const int TB = 256;
    dim3 blk(TB);
    dim3 gE((kE + TB - 1) / TB);
    dim3 g2E((2 * kE + TB - 1) / TB);
    dim3 gN(kNB);
    dim3 g8N((8 * kN + TB - 1) / TB);

    // CSR build
    hipMemsetAsync(deg, 0, kN * sizeof(int), stream);
    count_kernel<<<gE, blk, 0, stream>>>(Cdist, deg);
    partial_sum_kernel<<<dim3(kNB), blk, 0, stream>>>(deg, blkSum);
    scan_sums_kernel<<<dim3(1), blk, 0, stream>>>(blkSum, blkOff);
    scatter_scan_kernel<<<dim3(kNB), blk, 0, stream>>>(deg, blkOff, start);
    hipMemcpyAsync(cursor, start, kN * sizeof(int), hipMemcpyDeviceToDevice, stream);
    fill_kernel<<<gE, blk, 0, stream>>>(Cdist, cursor, inc);

    // degree-sorted dispatch order: per-block LDS hist -> scan -> scatter
    blk_hist_kernel<<<gN, blk, 0, stream>>>(deg, blkHist);
    sort_scan_kernel<<<dim3(1), dim3(1024), 0, stream>>>(blkHist, scanned);
    order_scatter_kernel<<<gN, blk, 0, stream>>>(deg, scanned, order);

    // predict + batch-minor layout, then per-slot invariants
    predict_kernel<<<gN, blk, 0, stream>>>(V, Vvel, Vw, Vcomp, Vmass, Vforce, PA, WC);
    slots_build_kernel<<<g2E, blk, 0, stream>>>(inc, Cdist, Cinit, WC, SS, ASrec);
    hipMemsetAsync(L, 0, (size_t)2 * kE * 8 * sizeof(float), stream);

    float* outV   = (float*)d_out;
    float* outVel = outV + (size_t)kBN * 3;

    for (int it = 0; it < kIter; ++it) {
        float4* src = (it & 1) ? PB : PA;
        float4* dst = (it & 1) ? PA : PB;
        if (it < kIter - 1) {
            sweep_kernel<false><<<g8N, blk, 0, stream>>>(src, dst, L, SS, ASrec, start,
                                                         order, V, outV, outVel);
        } else {
            sweep_kernel<true><<<g8N, blk, 0, stream>>>(src, dst, L, SS, ASrec, start,
                                                        order, V, outV, outVel);
        }
    }
}